// Round 9
// baseline (311.495 us; speedup 1.0000x reference)
//
#include <hip/hip_runtime.h>
#include <cmath>

#define HIDDEN 2048
#define NH 16
#define NKV 4
#define HD 128
#define SEQ 2048
#define BATCH 2

typedef unsigned short ushort_t;
typedef short bf16x8 __attribute__((ext_vector_type(8)));
typedef float f32x4 __attribute__((ext_vector_type(4)));
typedef ushort_t u16x4 __attribute__((ext_vector_type(4)));

__device__ __forceinline__ ushort_t f2bf(float f) {
    union { float f; unsigned int u; } v; v.f = f;
    unsigned int r = v.u + 0x7fffu + ((v.u >> 16) & 1u);
    return (ushort_t)(r >> 16);
}
__device__ __forceinline__ ushort_t f2bf_trunc(float f) {
    union { float f; unsigned int u; } v; v.f = f;
    return (ushort_t)(v.u >> 16);
}

__device__ __forceinline__ f32x4 mfma16(bf16x8 a, bf16x8 b, f32x4 c) {
    return __builtin_amdgcn_mfma_f32_16x16x32_bf16(a, b, c, 0, 0, 0);
}

// async global -> LDS, 16B per lane. LDS dst is wave-uniform base + lane*16.
__device__ __forceinline__ void load_lds16(const void* g, void* l) {
    __builtin_amdgcn_global_load_lds((const __attribute__((address_space(1))) unsigned int*)g,
                                     (__attribute__((address_space(3))) unsigned int*)l,
                                     16, 0, 0);
}

// Zero-conflict LDS tile family (r8-verified, SQ_LDS_BANK_CONFLICT==0 measured):
// [rows][32 shorts] (64-B row stride). Chunk c of row p stored at slot c^((p>>1)&3).
// Staging lane l: row p=l>>2, slot l&3, fetches global chunk (l&3)^((l>>3)&3).
// Reader of chunk q at row r uses slot q^((r>>1)&3) (row bases are multiples of 16).

// RoPE-pair column permutation (N-dim of WqkvT), applied at prep time for Q and K
// regions: within each 128-col head, frag order f -> pos(f) = (f&3)*2 + (f>>2),
// i.e. stored order f0,f4,f1,f5,f2,f6,f3,f7.  Any 32-aligned frag-pair (2m,2m+1)
// is then a complete RoPE pair (d, d+64) with identical lane assignment, so a
// BN=192 tile (1.5 heads) always contains whole pairs.  Inverse (epilogue):
// permuted pair-base pcb -> d = ((pcb>>5)&3)*16 + l16, partner d+64.

// ---------------- fused prep: weight transpose (z<4) + activation convert (z>=4) ----
// z=0: Wq -> WqkvT rows 0..2047 (pi-permuted) | z=1: Wk -> rows 2048..2559 (pi)
// z=2: Wv -> rows 2560..3071 | z=3: Wo -> WoT | z=4..11: hs fp32 -> Xb bf16
__global__ __launch_bounds__(256) void prep(const float* __restrict__ Wq,
                                            const float* __restrict__ Wk,
                                            const float* __restrict__ Wv,
                                            const float* __restrict__ Wo,
                                            ushort_t* __restrict__ WqkvT,
                                            ushort_t* __restrict__ WoT,
                                            const float* __restrict__ hs,
                                            ushort_t* __restrict__ Xb) {
    const int z = blockIdx.z;
    const int t = threadIdx.x;
    if (z >= 4) {
        int g = (((z - 4) * 32 + blockIdx.y) * 32 + blockIdx.x) * 256 + t;
        float4 v = ((const float4*)hs)[g];
        u16x4 o;
        o[0] = f2bf(v.x); o[1] = f2bf(v.y); o[2] = f2bf(v.z); o[3] = f2bf(v.w);
        ((u16x4*)Xb)[g] = o;
        return;
    }
    const float* W;
    ushort_t* WT;
    int N;
    if (z == 0)      { W = Wq; WT = WqkvT;                        N = 2048; }
    else if (z == 1) { W = Wk; WT = WqkvT + 2048ull * 2048;       N = 512;  }
    else if (z == 2) { W = Wv; WT = WqkvT + 2560ull * 2048;       N = 512;  }
    else             { W = Wo; WT = WoT;                          N = 2048; }
    const int K = 2048;
    const int n0 = blockIdx.x * 64, k0 = blockIdx.y * 64;
    if (n0 >= N) return;
    __shared__ ushort_t T[64][72];
    for (int idx = t; idx < 64 * 16; idx += 256) {
        int r = idx >> 4, c4 = (idx & 15) << 2;
        float4 v = *(const float4*)&W[(size_t)(k0 + r) * N + n0 + c4];
        T[r][c4 + 0] = f2bf(v.x); T[r][c4 + 1] = f2bf(v.y);
        T[r][c4 + 2] = f2bf(v.z); T[r][c4 + 3] = f2bf(v.w);
    }
    __syncthreads();
    for (int idx = t; idx < 64 * 16; idx += 256) {
        int n = idx >> 4, kg = (idx & 15) << 2;
        int c = n0 + n;
        int pr = c;
        if (z <= 1)  // pair-adjacent frag permutation within each 128-col head
            pr = (c & ~127) | ((((c >> 4) & 3) * 2 + ((c >> 6) & 1)) << 4) | (c & 15);
        u16x4 o;
        o[0] = T[kg + 0][n]; o[1] = T[kg + 1][n];
        o[2] = T[kg + 2][n]; o[3] = T[kg + 3][n];
        *(u16x4*)&WT[(size_t)pr * K + k0 + kg] = o;
    }
}

// ---------------- fused QKV GEMM: 256x192 tile, 8-phase counted-vmcnt ----------------
// Qkv = X[4096][2048] * WqkvT[3072][2048]^T (+bias, RoPE, stores).  N=3072 = 16 tiles
// of 192 -> grid 16x16 = 256 blocks = EXACT 1/CU fill (was 192/256 = 75%).
// 512 threads = 8 waves as 4 m-waves (64 rows) x 2 n-waves (96 cols = 6 frags);
// acc[4][6]; frag-pairs (2m,2m+1) are RoPE pairs via the prep permutation.
// BK=64 as 2 kc-planes of [rows][32] (zero-conflict family).  7 loads/tile:
// sA0,sA1 (2 each: both planes, 128 rows), sBa (p0 r0-127), sBb (p0 r128-191 +
// p1 r0-63, contiguous LDS), sBc (p1 r64-191).
// Phase reads:  P1 kc0 j012 (needs sA*,sBa,sBb) | P2 kc0 j345 (same) |
//               P3 kc1 j012 (needs +sBc)        | P4 kc1 j345 (same).
// Stage(u+1): P1:sA0  P2:sA1  P3:sBa+sBb  P4:sBc.
// Ledger: P1 vmcnt(3) [allows sBc(u)+sA0(u+1); guarantees sA*,sBa,sBb(u)];
//         P2 vmcnt(4) [allows sA0,sA1(u+1)+...; guarantees sBc(u) before P3 reads].
// Never drains to 0 mid-loop.  Prologue: 7 stages, vmcnt(1), barrier.
__global__ __launch_bounds__(512) void gemm_qkv(const ushort_t* __restrict__ A,
                                                const ushort_t* __restrict__ Bt,
                                                const float* __restrict__ bq,
                                                const float* __restrict__ bk,
                                                const float* __restrict__ bv,
                                                ushort_t* __restrict__ Qr,
                                                ushort_t* __restrict__ Kr,
                                                ushort_t* __restrict__ Vt,
                                                int K,
                                                const int* __restrict__ posids) {
    constexpr int APL = 256 * 32;  // A kc-plane (shorts)
    constexpr int BPL = 192 * 32;  // B kc-plane (shorts)
    __shared__ __align__(16) ushort_t Asb[2 * 2 * APL];  // 64 KB
    __shared__ __align__(16) ushort_t Bsb[2 * 2 * BPL];  // 48 KB
    const int tid = threadIdx.x;
    const int w = tid >> 6, lane = tid & 63, quad = lane >> 4, l16 = lane & 15;
    const int wr = w >> 1, wn = w & 1;  // 4x2 wave grid
    const int m0 = blockIdx.y * 256, n0 = blockIdx.x * 192;

    f32x4 acc[4][6];
#pragma unroll
    for (int i = 0; i < 4; i++)
#pragma unroll
        for (int j = 0; j < 6; j++)
#pragma unroll
            for (int e = 0; e < 4; e++) acc[i][j][e] = 0.0f;

    // staging: lane -> row l>>2 (16 rows/wave/load), swizzled chunk
    const int srow = lane >> 2;
    const int gc8 = (((lane & 3) ^ ((lane >> 3) & 3)) << 3);

    auto stageA = [&](int t, int buf, int ha) {  // 2 loads: 128 rows x both planes
        const ushort_t* g = A + (size_t)(m0 + ha * 128 + w * 16 + srow) * K + t * 64 + gc8;
        ushort_t* l = &Asb[buf * 2 * APL + (ha * 128 + w * 16) * 32];
        load_lds16(g, l);
        load_lds16(g + 32, l + APL);
    };
    auto stageBa = [&](int t, int buf) {  // p0 rows 0-127
        const ushort_t* g = Bt + (size_t)(n0 + w * 16 + srow) * K + t * 64 + gc8;
        load_lds16(g, &Bsb[buf * 2 * BPL + (w * 16) * 32]);
    };
    auto stageBb = [&](int t, int buf) {  // p0 r128-191 (w<4) + p1 r0-63 (w>=4)
        const int r  = (w < 4) ? (128 + w * 16 + srow) : ((w - 4) * 16 + srow);
        const int kc = (w < 4) ? 0 : 32;
        const ushort_t* g = Bt + (size_t)(n0 + r) * K + t * 64 + kc + gc8;
        load_lds16(g, &Bsb[buf * 2 * BPL + 4096 + w * 512]);  // contiguous across planes
    };
    auto stageBc = [&](int t, int buf) {  // p1 rows 64-191
        const ushort_t* g = Bt + (size_t)(n0 + 64 + w * 16 + srow) * K + t * 64 + 32 + gc8;
        load_lds16(g, &Bsb[buf * 2 * BPL + BPL + (64 + w * 16) * 32]);
    };

    const int slot = ((quad ^ ((l16 >> 1) & 3)) << 3);
    const int arow = (wr * 64 + l16) * 32 + slot;   // + i*512
    const int brow = (wn * 96 + l16) * 32 + slot;   // + j*512

    const int nt = K >> 6;

    // prologue: tile 0 fully staged; sBc(0) allowed outstanding (first read at P3,
    // guaranteed by P2's vmcnt(4))
    stageA(0, 0, 0); stageA(0, 0, 1);
    stageBa(0, 0); stageBb(0, 0); stageBc(0, 0);
    asm volatile("s_waitcnt vmcnt(1)" ::: "memory");
    __builtin_amdgcn_s_barrier();
    __builtin_amdgcn_sched_barrier(0);

    bf16x8 a[4];
    for (int u = 0; u < nt; ++u) {
        const int bu = u & 1, bn = bu ^ 1;
        const bool pf = (u + 1 < nt);
        const ushort_t* Ap0 = &Asb[bu * 2 * APL];
        const ushort_t* Ap1 = Ap0 + APL;
        const ushort_t* Bp0 = &Bsb[bu * 2 * BPL];
        const ushort_t* Bp1 = Bp0 + BPL;

        // ---- P1: kc0, j={0,1,2} ----
#pragma unroll
        for (int i = 0; i < 4; i++) a[i] = *(const bf16x8*)&Ap0[arow + i * 512];
        bf16x8 b0 = *(const bf16x8*)&Bp0[brow];
        bf16x8 b1 = *(const bf16x8*)&Bp0[brow + 512];
        bf16x8 b2 = *(const bf16x8*)&Bp0[brow + 1024];
        if (pf) { stageA(u + 1, bn, 0); asm volatile("s_waitcnt vmcnt(3)" ::: "memory"); }
        else    { asm volatile("s_waitcnt vmcnt(0)" ::: "memory"); }
        __builtin_amdgcn_s_barrier();
        __builtin_amdgcn_sched_barrier(0);
        __builtin_amdgcn_s_setprio(1);
#pragma unroll
        for (int i = 0; i < 4; i++) {
            acc[i][0] = mfma16(a[i], b0, acc[i][0]);
            acc[i][1] = mfma16(a[i], b1, acc[i][1]);
            acc[i][2] = mfma16(a[i], b2, acc[i][2]);
        }
        __builtin_amdgcn_s_setprio(0);
        __builtin_amdgcn_sched_barrier(0);
        __builtin_amdgcn_s_barrier();
        __builtin_amdgcn_sched_barrier(0);

        // ---- P2: kc0, j={3,4,5} ----
        bf16x8 b3 = *(const bf16x8*)&Bp0[brow + 1536];
        bf16x8 b4 = *(const bf16x8*)&Bp0[brow + 2048];
        bf16x8 b5 = *(const bf16x8*)&Bp0[brow + 2560];
        if (pf) { stageA(u + 1, bn, 1); asm volatile("s_waitcnt vmcnt(4)" ::: "memory"); }
        __builtin_amdgcn_s_barrier();
        __builtin_amdgcn_sched_barrier(0);
        __builtin_amdgcn_s_setprio(1);
#pragma unroll
        for (int i = 0; i < 4; i++) {
            acc[i][3] = mfma16(a[i], b3, acc[i][3]);
            acc[i][4] = mfma16(a[i], b4, acc[i][4]);
            acc[i][5] = mfma16(a[i], b5, acc[i][5]);
        }
        __builtin_amdgcn_s_setprio(0);
        __builtin_amdgcn_sched_barrier(0);
        __builtin_amdgcn_s_barrier();
        __builtin_amdgcn_sched_barrier(0);

        // ---- P3: kc1, j={0,1,2} ----
#pragma unroll
        for (int i = 0; i < 4; i++) a[i] = *(const bf16x8*)&Ap1[arow + i * 512];
        b0 = *(const bf16x8*)&Bp1[brow];
        b1 = *(const bf16x8*)&Bp1[brow + 512];
        b2 = *(const bf16x8*)&Bp1[brow + 1024];
        if (pf) { stageBa(u + 1, bn); stageBb(u + 1, bn); }
        __builtin_amdgcn_s_barrier();
        __builtin_amdgcn_sched_barrier(0);
        __builtin_amdgcn_s_setprio(1);
#pragma unroll
        for (int i = 0; i < 4; i++) {
            acc[i][0] = mfma16(a[i], b0, acc[i][0]);
            acc[i][1] = mfma16(a[i], b1, acc[i][1]);
            acc[i][2] = mfma16(a[i], b2, acc[i][2]);
        }
        __builtin_amdgcn_s_setprio(0);
        __builtin_amdgcn_sched_barrier(0);
        __builtin_amdgcn_s_barrier();
        __builtin_amdgcn_sched_barrier(0);

        // ---- P4: kc1, j={3,4,5} ----
        b3 = *(const bf16x8*)&Bp1[brow + 1536];
        b4 = *(const bf16x8*)&Bp1[brow + 2048];
        b5 = *(const bf16x8*)&Bp1[brow + 2560];
        if (pf) stageBc(u + 1, bn);
        __builtin_amdgcn_s_barrier();
        __builtin_amdgcn_sched_barrier(0);
        __builtin_amdgcn_s_setprio(1);
#pragma unroll
        for (int i = 0; i < 4; i++) {
            acc[i][3] = mfma16(a[i], b3, acc[i][3]);
            acc[i][4] = mfma16(a[i], b4, acc[i][4]);
            acc[i][5] = mfma16(a[i], b5, acc[i][5]);
        }
        __builtin_amdgcn_s_setprio(0);
        __builtin_amdgcn_sched_barrier(0);
        __builtin_amdgcn_s_barrier();
        __builtin_amdgcn_sched_barrier(0);
    }

    // ---- epilogue: per frag-pair, region + inverse-permutation ----
    // pair base (wave-uniform): pcb_m = n0 + wn*96 + m*32; even permuted-frag index
    // -> orig d = ((pcb>>5)&3)*16 + l16, partner d+64.
    const float scale = 0.08838834764831845f;
    int   dm_[3]; float fr_[3];
#pragma unroll
    for (int m = 0; m < 3; m++) {
        int pcb = n0 + wn * 96 + m * 32;
        dm_[m] = (((pcb < 2560 ? pcb : 0) >> 5) & 3) * 16 + l16;  // valid for Q/K pairs
        fr_[m] = __expf(-0.21586735246819178f * (float)dm_[m]);
    }
#pragma unroll
    for (int i = 0; i < 4; i++)
#pragma unroll
        for (int r = 0; r < 4; r++) {
            int row = m0 + wr * 64 + i * 16 + quad * 4 + r;  // b*SEQ + s
            int b = row >> 11, s = row & (SEQ - 1);
            float pos = (float)posids[row];
#pragma unroll
            for (int m = 0; m < 3; m++) {
                int pcb = n0 + wn * 96 + m * 32;
                if (pcb < 2048) {  // Q: RoPE + scale
                    int h = pcb >> 7;
                    int d = dm_[m];
                    float sn, cs;
                    __sincosf(pos * fr_[m], &sn, &cs);
                    float x1 = acc[i][2 * m][r]     + bq[h * 128 + d];
                    float x2 = acc[i][2 * m + 1][r] + bq[h * 128 + d + 64];
                    size_t ob = ((size_t)(b * NH + h) * SEQ + s) * HD;
                    Qr[ob + d]      = f2bf((x1 * cs - x2 * sn) * scale);
                    Qr[ob + d + 64] = f2bf((x2 * cs + x1 * sn) * scale);
                } else if (pcb < 2560) {  // K: RoPE
                    int c = pcb - 2048;
                    int h = c >> 7;
                    int d = dm_[m];
                    float sn, cs;
                    __sincosf(pos * fr_[m], &sn, &cs);
                    float x1 = acc[i][2 * m][r]     + bk[h * 128 + d];
                    float x2 = acc[i][2 * m + 1][r] + bk[h * 128 + d + 64];
                    size_t ob = ((size_t)(b * NKV + h) * SEQ + s) * HD;
                    Kr[ob + d]      = f2bf(x1 * cs - x2 * sn);
                    Kr[ob + d + 64] = f2bf(x2 * cs + x1 * sn);
                } else {  // V: two independent frags, identity cols, transposed store
#pragma unroll
                    for (int q = 0; q < 2; q++) {
                        int c = pcb + q * 16 - 2560;  // + l16
                        int h = c >> 7;
                        int d = (c & 127) + l16;
                        float v = acc[i][2 * m + q][r] + bv[c + l16];
                        Vt[((size_t)(b * NKV + h) * HD + d) * SEQ + s] = f2bf(v);
                    }
                }
            }
        }
}

// ---------------- 128x256-tile proj GEMM, 8-phase counted-vmcnt (r8-verified) ------
template <int MODE, int BMH>
__global__ __launch_bounds__(512) void gemm256(const ushort_t* __restrict__ A,
                                               const ushort_t* __restrict__ Bt,
                                               const float* __restrict__ bias,
                                               const float* __restrict__ bias2,
                                               const float* __restrict__ bias3,
                                               void* __restrict__ out,
                                               void* __restrict__ out2,
                                               void* __restrict__ out3,
                                               int M, int N, int K,
                                               const int* __restrict__ posids) {
    constexpr int IM = 4 * BMH;
    constexpr int APL = BMH * 128 * 32;
    constexpr int BPL = 256 * 32;
    __shared__ __align__(16) ushort_t Asb[2 * 2 * APL];
    __shared__ __align__(16) ushort_t Bsb[2 * 2 * BPL];
    const int tid = threadIdx.x;
    const int w = tid >> 6, lane = tid & 63, quad = lane >> 4, l16 = lane & 15;
    const int wr = w >> 2, wc = w & 3;
    const int m0 = blockIdx.y * (128 * BMH), n0 = blockIdx.x * 256;

    f32x4 acc[IM][4];
#pragma unroll
    for (int i = 0; i < IM; i++)
#pragma unroll
        for (int j = 0; j < 4; j++)
#pragma unroll
            for (int e = 0; e < 4; e++) acc[i][j][e] = 0.0f;

    const int srow = lane >> 2;
    const int gc8 = (((lane & 3) ^ ((lane >> 3) & 3)) << 3);

    auto stageA = [&](int t, int buf, int ha) {
        const ushort_t* g = A + (size_t)(m0 + ha * 128 + w * 16 + srow) * K + t * 64 + gc8;
        ushort_t* l = &Asb[buf * 2 * APL + (ha * 128 + w * 16) * 32];
        load_lds16(g, l);
        load_lds16(g + 32, l + APL);
    };
    auto stageB = [&](int t, int buf, int ha) {
        const ushort_t* g = Bt + (size_t)(n0 + ha * 128 + w * 16 + srow) * K + t * 64 + gc8;
        ushort_t* l = &Bsb[buf * 2 * BPL + (ha * 128 + w * 16) * 32];
        load_lds16(g, l);
        load_lds16(g + 32, l + BPL);
    };

    const int slot = ((quad ^ ((l16 >> 1) & 3)) << 3);
    const int arow = (wr * (64 * BMH) + l16) * 32 + slot;
    const int brow = (wc * 16 + l16) * 32 + slot;

    const int nt = K >> 6;

    stageA(0, 0, 0);
    if constexpr (BMH == 2) stageA(0, 0, 1);
    stageB(0, 0, 0);
    stageB(0, 0, 1);
    asm volatile("s_waitcnt vmcnt(2)" ::: "memory");
    __builtin_amdgcn_s_barrier();
    __builtin_amdgcn_sched_barrier(0);

    bf16x8 a[IM];
    for (int u = 0; u < nt; ++u) {
        const int bu = u & 1, bn = bu ^ 1;
        const bool pf = (u + 1 < nt);
        const ushort_t* Ap0 = &Asb[bu * 2 * APL];
        const ushort_t* Ap1 = Ap0 + APL;
        const ushort_t* Bp0 = &Bsb[bu * 2 * BPL];
        const ushort_t* Bp1 = Bp0 + BPL;

        // ---- P1 ----
#pragma unroll
        for (int i = 0; i < IM; i++) a[i] = *(const bf16x8*)&Ap0[arow + i * 512];
        bf16x8 b0 = *(const bf16x8*)&Bp0[brow];
        bf16x8 b1 = *(const bf16x8*)&Bp0[brow + 2048];
        if (pf) { stageA(u + 1, bn, 0); asm volatile("s_waitcnt vmcnt(2)" ::: "memory"); }
        else    { asm volatile("s_waitcnt vmcnt(0)" ::: "memory"); }
        __builtin_amdgcn_s_barrier();
        __builtin_amdgcn_sched_barrier(0);
        __builtin_amdgcn_s_setprio(1);
#pragma unroll
        for (int i = 0; i < IM; i++) {
            acc[i][0] = mfma16(a[i], b0, acc[i][0]);
            acc[i][1] = mfma16(a[i], b1, acc[i][1]);
        }
        __builtin_amdgcn_s_setprio(0);
        __builtin_amdgcn_sched_barrier(0);
        __builtin_amdgcn_s_barrier();
        __builtin_amdgcn_sched_barrier(0);

        // ---- P2 ----
        bf16x8 b2 = *(const bf16x8*)&Bp0[brow + 4096];
        bf16x8 b3 = *(const bf16x8*)&Bp0[brow + 6144];
        if (pf) {
            if constexpr (BMH == 2) stageA(u + 1, bn, 1);
            else                    stageB(u + 1, bn, 0);
        }
        __builtin_amdgcn_s_barrier();
        __builtin_amdgcn_sched_barrier(0);
        __builtin_amdgcn_s_setprio(1);
#pragma unroll
        for (int i = 0; i < IM; i++) {
            acc[i][2] = mfma16(a[i], b2, acc[i][2]);
            acc[i][3] = mfma16(a[i], b3, acc[i][3]);
        }
        __builtin_amdgcn_s_setprio(0);
        __builtin_amdgcn_sched_barrier(0);
        __builtin_amdgcn_s_barrier();
        __builtin_amdgcn_sched_barrier(0);

        // ---- P3 ----
#pragma unroll
        for (int i = 0; i < IM; i++) a[i] = *(const bf16x8*)&Ap1[arow + i * 512];
        b0 = *(const bf16x8*)&Bp1[brow];
        b1 = *(const bf16x8*)&Bp1[brow + 2048];
        if (pf) {
            if constexpr (BMH == 2) stageB(u + 1, bn, 0);
            else                    stageB(u + 1, bn, 1);
        }
        __builtin_amdgcn_s_barrier();
        __builtin_amdgcn_sched_barrier(0);
        __builtin_amdgcn_s_setprio(1);
#pragma unroll
        for (int i = 0; i < IM; i++) {
            acc[i][0] = mfma16(a[i], b0, acc[i][0]);
            acc[i][1] = mfma16(a[i], b1, acc[i][1]);
        }
        __builtin_amdgcn_s_setprio(0);
        __builtin_amdgcn_sched_barrier(0);
        __builtin_amdgcn_s_barrier();
        __builtin_amdgcn_sched_barrier(0);

        // ---- P4 ----
        b2 = *(const bf16x8*)&Bp1[brow + 4096];
        b3 = *(const bf16x8*)&Bp1[brow + 6144];
        if (pf) {
            if constexpr (BMH == 2) stageB(u + 1, bn, 1);
            asm volatile("s_waitcnt vmcnt(2)" ::: "memory");
        }
        __builtin_amdgcn_s_barrier();
        __builtin_amdgcn_sched_barrier(0);
        __builtin_amdgcn_s_setprio(1);
#pragma unroll
        for (int i = 0; i < IM; i++) {
            acc[i][2] = mfma16(a[i], b2, acc[i][2]);
            acc[i][3] = mfma16(a[i], b3, acc[i][3]);
        }
        __builtin_amdgcn_s_setprio(0);
        __builtin_amdgcn_sched_barrier(0);
        __builtin_amdgcn_s_barrier();
        __builtin_amdgcn_sched_barrier(0);
    }

    if (MODE == 0) {
        float* O = (float*)out;
#pragma unroll
        for (int i = 0; i < IM; i++)
#pragma unroll
            for (int r = 0; r < 4; r++) {
                int row = m0 + wr * (64 * BMH) + i * 16 + quad * 4 + r;
#pragma unroll
                for (int j = 0; j < 4; j++) {
                    int col = n0 + (wc + 4 * j) * 16 + l16;
                    O[(size_t)row * N + col] = acc[i][j][r] + bias[col];
                }
            }
    }
}

// ---------------- causal GQA flash attention, balanced-pair Q64 subtiles ----------------
// (unchanged from r8 -- verified)
__global__ __launch_bounds__(256) void flash(const ushort_t* __restrict__ Qr,
                                             const ushort_t* __restrict__ Kr,
                                             const ushort_t* __restrict__ Vt,
                                             ushort_t* __restrict__ Attn) {
    __shared__ __align__(16) ushort_t Ksh[2 * 4 * 64 * 32];   // 32 KB
    __shared__ __align__(16) ushort_t Vsh[2 * 2 * 128 * 32];  // 32 KB
    __shared__ __align__(16) ushort_t Ps[4 * 16 * 72];        // 9 KB, per-wave
    const int tid = threadIdx.x;
    const int w = tid >> 6, lane = tid & 63, quad = lane >> 4, l16 = lane & 15;
    const int x = blockIdx.x, h = blockIdx.y, b = blockIdx.z;
    const int qa = x, qb = 31 - x;
    const int nkt = qb + 1;
    const int hkv = h >> 2;
    const ushort_t* Kg = Kr + ((size_t)(b * NKV + hkv) * SEQ) * HD;
    const ushort_t* Vg = Vt + ((size_t)(b * NKV + hkv) * HD) * SEQ;

    const int p = lane >> 2;
    const int gc8 = (((lane & 3) ^ ((lane >> 3) & 3)) << 3);
    const ushort_t* kst = Kg + (size_t)p * HD + w * 32 + gc8;
    const ushort_t* vst = Vg + (size_t)((w & 1) * 64 + p) * SEQ + (w >> 1) * 32 + gc8;
    ushort_t* ksl = Ksh + w * 2048;
    ushort_t* vsl = Vsh + (w >> 1) * 4096 + (w & 1) * 2048;

    auto stage = [&](int bi, int kv0) {
        const ushort_t* gk = kst + (size_t)kv0 * HD;
        ushort_t* lk = ksl + bi * 8192;
        load_lds16(gk, lk);
        load_lds16(gk + (size_t)16 * HD, lk + 512);
        load_lds16(gk + (size_t)32 * HD, lk + 1024);
        load_lds16(gk + (size_t)48 * HD, lk + 1536);
        const ushort_t* gv = vst + kv0;
        ushort_t* lv = vsl + bi * 8192;
        load_lds16(gv, lv);
        load_lds16(gv + (size_t)16 * SEQ, lv + 512);
        load_lds16(gv + (size_t)32 * SEQ, lv + 1024);
        load_lds16(gv + (size_t)48 * SEQ, lv + 1536);
    };

    bf16x8 aq[2][4];
#pragma unroll
    for (int st = 0; st < 2; st++) {
        const int qst = st ? qb : qa;
        const size_t qrow = ((size_t)(b * NH + h) * SEQ + qst * 64 + w * 16 + l16) * HD;
#pragma unroll
        for (int kc = 0; kc < 4; kc++)
            aq[st][kc] = *(const bf16x8*)&Qr[qrow + kc * 32 + quad * 8];
    }

    f32x4 o[2][8];
#pragma unroll
    for (int st = 0; st < 2; st++)
#pragma unroll
        for (int j = 0; j < 8; j++)
#pragma unroll
            for (int e = 0; e < 4; e++) o[st][j][e] = 0.0f;
    f32x4 ls2[2];
#pragma unroll
    for (int st = 0; st < 2; st++)
        for (int e = 0; e < 4; e++) ls2[st][e] = 0.0f;
    bf16x8 ones;
#pragma unroll
    for (int e = 0; e < 8; e++) ones[e] = (short)0x3F80;

    ushort_t* Pw = &Ps[w * 16 * 72];
    const int rsw8 = ((l16 >> 1) & 3) << 3;

    stage(0, 0);
    asm volatile("s_waitcnt vmcnt(0)" ::: "memory");
    __builtin_amdgcn_s_barrier();

    for (int kt = 0; kt < nkt; kt++) {
        const int kv0 = kt * 64;
        const int cur = kt & 1;
        if (kt + 1 < nkt) {
            stage(cur ^ 1, kv0 + 64);
            asm volatile("s_waitcnt vmcnt(8)" ::: "memory");
        } else {
            asm volatile("s_waitcnt vmcnt(0)" ::: "memory");
        }
        __builtin_amdgcn_s_barrier();

        const ushort_t* Kb = Ksh + cur * 8192;
        const ushort_t* Vb = Vsh + cur * 8192;

#pragma unroll
        for (int st = 0; st < 2; st++) {
            const int qst = st ? qb : qa;
            if (st == 0 && kt > qa) continue;

            f32x4 sa[4];
#pragma unroll
            for (int nt = 0; nt < 4; nt++)
#pragma unroll
                for (int e = 0; e < 4; e++) sa[nt][e] = 0.0f;
#pragma unroll
            for (int kc = 0; kc < 4; kc++) {
#pragma unroll
                for (int nt = 0; nt < 4; nt++) {
                    bf16x8 bk = *(const bf16x8*)&Kb[kc * 2048 + nt * 512 + l16 * 32 +
                                                    ((quad * 8) ^ rsw8)];
                    sa[nt] = mfma16(aq[st][kc], bk, sa[nt]);
                }
            }

            if (kt == qst) {
#pragma unroll
                for (int nt = 0; nt < 4; nt++)
#pragma unroll
                    for (int r = 0; r < 4; r++) {
                        int kvg = kv0 + nt * 16 + l16;
                        int qg = qst * 64 + w * 16 + quad * 4 + r;
                        if (kvg > qg) sa[nt][r] = -1e30f;
                    }
            }

#pragma unroll
            for (int nt = 0; nt < 4; nt++)
#pragma unroll
                for (int r = 0; r < 4; r++)
                    Pw[(quad * 4 + r) * 72 + nt * 16 + l16] = f2bf_trunc(__expf(sa[nt][r]));

#pragma unroll
            for (int kc = 0; kc < 2; kc++) {
                bf16x8 ap = *(const bf16x8*)&Pw[l16 * 72 + kc * 32 + quad * 8];
                ls2[st] = mfma16(ap, ones, ls2[st]);
#pragma unroll
                for (int j = 0; j < 8; j++) {
                    bf16x8 bv = *(const bf16x8*)&Vb[kc * 4096 + (j * 16 + l16) * 32 +
                                                    ((quad * 8) ^ rsw8)];
                    o[st][j] = mfma16(ap, bv, o[st][j]);
                }
            }
        }
        asm volatile("s_barrier" ::: "memory");
    }

#pragma unroll
    for (int st = 0; st < 2; st++) {
        const int qst = st ? qb : qa;
#pragma unroll
        for (int r = 0; r < 4; r++) {
            float inv = 1.0f / ls2[st][r];
            int row = b * SEQ + qst * 64 + w * 16 + quad * 4 + r;
            size_t obase = (size_t)row * HIDDEN + h * HD;
#pragma unroll
            for (int j = 0; j < 8; j++) Attn[obase + j * 16 + l16] = f2bf(o[st][j][r] * inv);
        }
    }
}

extern "C" void kernel_launch(void* const* d_in, const int* in_sizes, int n_in,
                              void* d_out, int out_size, void* d_ws, size_t ws_size,
                              hipStream_t stream) {
    const float* hs = (const float*)d_in[0];
    const int* posids = (const int*)d_in[1];
    const float* Wq = (const float*)d_in[2];
    const float* bq = (const float*)d_in[3];
    const float* Wk = (const float*)d_in[4];
    const float* bk = (const float*)d_in[5];
    const float* Wv = (const float*)d_in[6];
    const float* bv = (const float*)d_in[7];
    const float* Wo = (const float*)d_in[8];
    const float* bo = (const float*)d_in[9];
    float* out = (float*)d_out;

    char* ws = (char*)d_ws;
    size_t off = 0;
    auto alloc = [&](size_t bytes) {
        char* p = ws + off;
        off += (bytes + 255) & ~(size_t)255;
        return p;
    };
    ushort_t* Xb     = (ushort_t*)alloc(4096ull * 2048 * 2);
    ushort_t* WqkvT  = (ushort_t*)alloc(3072ull * 2048 * 2);
    ushort_t* WoT    = (ushort_t*)alloc(2048ull * 2048 * 2);
    ushort_t* Qr     = (ushort_t*)alloc((size_t)BATCH * NH * SEQ * HD * 2);
    ushort_t* Kr     = (ushort_t*)alloc((size_t)BATCH * NKV * SEQ * HD * 2);
    ushort_t* Vtr    = (ushort_t*)alloc((size_t)BATCH * NKV * HD * SEQ * 2);
    ushort_t* Attn   = (ushort_t*)alloc(4096ull * 2048 * 2);

    prep<<<dim3(32, 32, 12), 256, 0, stream>>>(Wq, Wk, Wv, Wo, WqkvT, WoT, hs, Xb);

    gemm_qkv<<<dim3(16, 16), 512, 0, stream>>>(Xb, WqkvT, bq, bk, bv,
                                               Qr, Kr, Vtr, 2048, posids);

    flash<<<dim3(16, NH, BATCH), 256, 0, stream>>>(Qr, Kr, Vtr, Attn);

    gemm256<0, 1><<<dim3(8, 32), 512, 0, stream>>>(Attn, WoT, bo, nullptr, nullptr,
                                                   out, nullptr, nullptr, 4096, 2048, 2048, nullptr);
}